// Round 13
// baseline (138.091 us; speedup 1.0000x reference)
//
#include <hip/hip_runtime.h>
#include <hip/hip_bf16.h>

#define CDIM 512
#define NTOK 4096
#define NH 4
#define DH 128
#define NGRP 32
#define EPS 1e-5f
#define KVBLK 64

typedef __attribute__((ext_vector_type(8))) short bf16x8;
typedef __attribute__((ext_vector_type(4))) short short4v;
typedef __attribute__((ext_vector_type(4))) float f32x4;
typedef __attribute__((ext_vector_type(16))) float f32x16;
typedef __attribute__((ext_vector_type(2))) unsigned int u32x2;

__device__ inline unsigned short f2bf(float f){
  unsigned int u = __float_as_uint(f);
  u = (u + 0x7fffu + ((u >> 16) & 1u)) >> 16;
  return (unsigned short)u;
}

__device__ inline float bf2f(unsigned short u){
  return __uint_as_float(((unsigned int)u) << 16);
}

__device__ inline f32x4 mfma_bf16(bf16x8 a, bf16x8 b, f32x4 c){
  asm("v_mfma_f32_16x16x32_bf16 %0, %1, %2, %0" : "+v"(c) : "v"(a), "v"(b));
  return c;
}

__device__ inline f32x16 mfma32(bf16x8 a, bf16x8 b, f32x16 c){
  asm("v_mfma_f32_32x32x16_bf16 %0, %1, %2, %0" : "+v"(c) : "v"(a), "v"(b));
  return c;
}

__device__ inline unsigned int cvtpk(float lo, float hi){
  unsigned int r;
  asm("v_cvt_pk_bf16_f32 %0, %1, %2" : "=v"(r) : "v"(lo), "v"(hi));
  return r;
}

#define GLD16(gsrc, ldst) \
  __builtin_amdgcn_global_load_lds((__attribute__((address_space(1))) const void*)(gsrc), \
                                   (__attribute__((address_space(3))) void*)(ldst), 16, 0, 0)

// P = exp(scale*(s-m)) = exp2(s*KSC - m*KSC)
#define KSC (0.088388347648318447f * 1.4426950408889634f)
#define INV_KSC (1.0f / KSC)
#define THR_RAW 60.0f
#define THR_K (THR_RAW * KSC)

// ---------------- weight fp32 -> bf16 ----------------
__global__ __launch_bounds__(256) void k_convert(const float* __restrict__ qkv_w,
                                                 const float* __restrict__ proj_w,
                                                 unsigned short* __restrict__ qw,
                                                 unsigned short* __restrict__ pw){
  int stride = gridDim.x * blockDim.x;
  int i0 = blockIdx.x * blockDim.x + threadIdx.x;
  for (int i = i0; i < 3*CDIM*CDIM; i += stride) qw[i] = f2bf(qkv_w[i]);
  for (int i = i0; i < CDIM*CDIM; i += stride)   pw[i] = f2bf(proj_w[i]);
}

// ---------------- groupnorm stats: one block per group ----------------
__global__ __launch_bounds__(256) void k_gnstats(const float* __restrict__ x,
                                                 float* __restrict__ stats){
  const int g = blockIdx.x, t = threadIdx.x;
  const f32x4* p = (const f32x4*)(x + (size_t)g * (16*NTOK));
  float s = 0.f, ss = 0.f;
  for (int i = t; i < 16*NTOK/4; i += 256){
    f32x4 v = p[i];
    s  += v[0]+v[1]+v[2]+v[3];
    ss += v[0]*v[0]+v[1]*v[1]+v[2]*v[2]+v[3]*v[3];
  }
  for (int off = 32; off > 0; off >>= 1){ s += __shfl_down(s, off); ss += __shfl_down(ss, off); }
  __shared__ float rs[4], rss[4];
  if ((t & 63) == 0){ rs[t>>6] = s; rss[t>>6] = ss; }
  __syncthreads();
  if (t == 0){
    float S  = rs[0]+rs[1]+rs[2]+rs[3];
    float SS = rss[0]+rss[1]+rss[2]+rss[3];
    const float inv = 1.f / (float)(16*NTOK);
    float mu  = S * inv;
    float var = SS * inv - mu*mu;
    stats[g]        = mu;
    stats[NGRP + g] = rsqrtf(var + EPS);
  }
}

// ---------------- GN apply + transpose: x (C,N) fp32 -> h_t (N,C) bf16 ----------------
__global__ __launch_bounds__(256) void k_gnapply(const float* __restrict__ x,
                                                 const float* __restrict__ stats,
                                                 const float* __restrict__ nw,
                                                 const float* __restrict__ nbias,
                                                 unsigned short* __restrict__ h_t){
  __shared__ float tile[64][68];
  const int n0 = blockIdx.x * 64, c0 = blockIdx.y * 64;
  const int t = threadIdx.x;
  {
    const int cl = t >> 2;
    #pragma unroll
    for (int i = 0; i < 4; i++){
      const int f4 = (t & 3) + i*4;
      *(f32x4*)&tile[cl][f4*4] = *(const f32x4*)(x + (size_t)(c0+cl)*NTOK + n0 + f4*4);
    }
  }
  __syncthreads();
  const int nl = t >> 2, cb = (t & 3) * 16;
  unsigned short ov[16] __attribute__((aligned(8)));
  #pragma unroll
  for (int j = 0; j < 16; j++){
    const int c = c0 + cb + j;
    const int grp = c >> 4;
    const float val = (tile[cb+j][nl] - stats[grp]) * stats[NGRP+grp] * nw[c] + nbias[c];
    ov[j] = f2bf(val);
  }
  unsigned short* dst = h_t + (size_t)(n0+nl)*CDIM + c0 + cb;
  #pragma unroll
  for (int j = 0; j < 4; j++) *(short4v*)(dst + j*4) = *(const short4v*)(ov + j*4);
}

// ---------------- GEMM: A (M,K) bf16 row-major, Bt (N,K) bf16 row-major ----------------
template<int MODE>
__global__ __launch_bounds__(256) void k_gemm(const unsigned short* __restrict__ A,
                                              const unsigned short* __restrict__ Bt,
                                              const float* __restrict__ bias,
                                              const float* __restrict__ xres,
                                              unsigned short* __restrict__ q_t,
                                              unsigned short* __restrict__ k_t,
                                              unsigned short* __restrict__ vbuf,
                                              float* __restrict__ out,
                                              int K)
{
  __shared__ unsigned short Asm[128*32];
  __shared__ unsigned short Bsm[128*32];
  const int m0 = blockIdx.y * 128, n0 = blockIdx.x * 128;
  const int t = threadIdx.x;
  const int lane = t & 63, w = t >> 6;
  const int lo = lane & 15, g = lane >> 4;
  const int wr = w >> 1, wc = w & 1;
  f32x4 acc[4][4];
  #pragma unroll
  for (int i=0;i<4;i++)
    #pragma unroll
    for (int j=0;j<4;j++) acc[i][j] = f32x4{0.f,0.f,0.f,0.f};

  const int row = t >> 2, cb8 = (t & 3) * 8;
  for (int k0 = 0; k0 < K; k0 += 32){
    __syncthreads();
    *(bf16x8*)(Asm + row*32 + cb8)      = *(const bf16x8*)(A  + (size_t)(m0+row)*K    + k0 + cb8);
    *(bf16x8*)(Asm + (row+64)*32 + cb8) = *(const bf16x8*)(A  + (size_t)(m0+row+64)*K + k0 + cb8);
    *(bf16x8*)(Bsm + row*32 + cb8)      = *(const bf16x8*)(Bt + (size_t)(n0+row)*K    + k0 + cb8);
    *(bf16x8*)(Bsm + (row+64)*32 + cb8) = *(const bf16x8*)(Bt + (size_t)(n0+row+64)*K + k0 + cb8);
    __syncthreads();
    bf16x8 af[4], bfr[4];
    #pragma unroll
    for (int i=0;i<4;i++) af[i]  = *(const bf16x8*)(Asm + (wr*64 + i*16 + lo)*32 + g*8);
    #pragma unroll
    for (int j=0;j<4;j++) bfr[j] = *(const bf16x8*)(Bsm + (wc*64 + j*16 + lo)*32 + g*8);
    #pragma unroll
    for (int i=0;i<4;i++)
      #pragma unroll
      for (int j=0;j<4;j++)
        acc[i][j] = mfma_bf16(af[i], bfr[j], acc[i][j]);
  }

  if constexpr (MODE == 0){
    const int sQ = m0 >> 9;
    const int hh = (m0 >> 7) & 3;
    #pragma unroll
    for (int i=0;i<4;i++){
      const int ddb = wr*64 + i*16 + g*4;
      const int ob  = m0 + ddb;
      float b[4];
      #pragma unroll
      for (int r=0;r<4;r++) b[r] = bias[ob + r];
      #pragma unroll
      for (int j=0;j<4;j++){
        const int n = n0 + wc*64 + j*16 + lo;
        if (sQ < 2){
          unsigned short pk[4] __attribute__((aligned(8)));
          #pragma unroll
          for (int r=0;r<4;r++) pk[r] = f2bf(acc[i][j][r] + b[r]);
          unsigned short* dst = (sQ == 0 ? q_t : k_t) + ((size_t)hh*NTOK + n)*DH + ddb;
          *(short4v*)dst = *(const short4v*)pk;
        } else {
          #pragma unroll
          for (int r=0;r<4;r++)
            vbuf[((size_t)hh*DH + ddb + r)*NTOK + n] = f2bf(acc[i][j][r] + b[r]);
        }
      }
    }
  } else {
    #pragma unroll
    for (int i=0;i<4;i++){
      const int ob = m0 + wr*64 + i*16 + g*4;
      float b[4];
      #pragma unroll
      for (int r=0;r<4;r++) b[r] = bias[ob + r];
      #pragma unroll
      for (int j=0;j<4;j++){
        const int n = n0 + wc*64 + j*16 + lo;
        #pragma unroll
        for (int r=0;r<4;r++){
          size_t idx = (size_t)(ob + r)*NTOK + n;
          out[idx] = acc[i][j][r] + b[r] + xres[idx];
        }
      }
    }
  }
}

// ---------------- flash attention: 4-wave blocks, kv-split NS, 3 blocks/CU target ----------------
// Round-12-verified math (swapped QK^T, in-lane softmax, Pt LDS round-trip).
// 256 threads / 4 waves / 128 q rows; single-buffered K/V; LDS 52.2 KB and
// 168 unified regs/wave -> HW fits 3 blocks/CU when the grid supplies them.
// NS=8: blockIdx.x%8==split -> all blocks of a split land on one XCD (L2 locality).
template<int NS>
__global__ __launch_bounds__(256, 2) void k_attn(const unsigned short* __restrict__ q_t,
                                                 const unsigned short* __restrict__ k_t,
                                                 const unsigned short* __restrict__ vbuf,
                                                 unsigned short* __restrict__ opart,
                                                 float* __restrict__ mlbuf){
  const int TPS = NTOK/KVBLK/NS;
  const int h = blockIdx.y;
  const int qt = blockIdx.x / NS, split = blockIdx.x % NS;
  const int t = threadIdx.x, w = t >> 6, lane = t & 63;
  const int la = lane & 31, hi = lane >> 5;
  const int s15 = la & 15, s7 = la & 7;
  const int nbq = qt * 128 + w * 32;

  __shared__ __align__(16) unsigned short Ksm[64*128];
  __shared__ __align__(16) unsigned short Vsm[128*64];
  __shared__ __align__(16) unsigned short Pt[4][32][76];   // [wave][q][kv], 152B stride

  const unsigned short* kg = k_t  + (size_t)h*NTOK*DH;
  const unsigned short* vg = vbuf + (size_t)h*DH*NTOK;

  auto stage = [&](int mt){
    const unsigned short* kgm = kg + (size_t)mt*KVBLK*DH;
    const unsigned short* vgm = vg + mt*KVBLK;
    #pragma unroll
    for (int rnd = 0; rnd < 4; rnd++){       // K: 1024 chunks / 256 threads
      const int c = rnd*256 + t;
      const int row = c >> 4, col = c & 15;
      GLD16(kgm + (size_t)row*DH + ((col ^ (row & 15))*8), &Ksm[c*8]);
    }
    #pragma unroll
    for (int rnd = 0; rnd < 4; rnd++){       // V: 1024 chunks / 256 threads
      const int c = rnd*256 + t;
      const int row = c >> 3, col = c & 7;
      GLD16(vgm + (size_t)row*NTOK + ((col ^ (row & 7))*8), &Vsm[c*8]);
    }
  };

  // Q as B-operand: col = q = la, k-slice d = ks*16 + hi*8 + j
  bf16x8 qa[8];
  {
    const unsigned short* qr = q_t + ((size_t)h*NTOK + nbq + la)*DH + hi*8;
    #pragma unroll
    for (int ks=0;ks<8;ks++) qa[ks] = *(const bf16x8*)(qr + ks*16);
  }

  float mk = -1e30f;      // running max * KSC for q = la
  float lsum = 0.f;       // own-hi partial row sum for q = la
  f32x16 oacc[4];         // O[d = dt*32 + crow(r,hi)][q = la]
  #pragma unroll
  for (int dt=0;dt<4;dt++)
    #pragma unroll
    for (int r=0;r<16;r++) oacc[dt][r] = 0.f;

  const int mt0 = split * TPS;
  for (int it = 0; it < TPS; it++){
    __syncthreads();                 // all waves done reading previous tile
    stage(mt0 + it);
    __syncthreads();                 // stage drained (compiler emits vmcnt(0) before barrier)

    const unsigned short* Ks = Ksm;
    const unsigned short* Vs = Vsm;
    unsigned short* Pw = &Pt[w][0][0];

    #pragma unroll
    for (int half = 0; half < 2; half++){
      // swapped QK^T: A = K rows (kv = half*32 + la), B = Q cols (q = la)
      f32x16 s;
      #pragma unroll
      for (int r=0;r<16;r++) s[r] = 0.f;
      __builtin_amdgcn_s_setprio(1);
      #pragma unroll
      for (int ks=0; ks<8; ks++){
        bf16x8 kf = *(const bf16x8*)(Ks + (half*32 + la)*128 + (((2*ks + hi) ^ s15) * 8));
        s = mfma32(kf, qa[ks], s);
      }
      __builtin_amdgcn_s_setprio(0);
      // in-lane max + partner-hi combine; defer-max
      float hmax = s[0];
      #pragma unroll
      for (int r=1;r<16;r++) hmax = fmaxf(hmax, s[r]);
      hmax = fmaxf(hmax, __shfl_xor(hmax, 32));
      const float hk = hmax * KSC;
      if (!__all(hk <= mk + THR_K)){
        const float mnk = fmaxf(mk, hk);
        const float al  = exp2f(mk - mnk);
        mk = mnk;
        lsum *= al;
        #pragma unroll
        for (int dt=0;dt<4;dt++)
          #pragma unroll
          for (int r=0;r<16;r++) oacc[dt][r] *= al;
      }
      // exp in place + own-lane sum; pack -> Pt[q=la][kv]
      #pragma unroll
      for (int r=0;r<16;r++){
        s[r] = exp2f(fmaf(s[r], KSC, -mk));
        lsum += s[r];
      }
      #pragma unroll
      for (int g2=0; g2<4; g2++){
        u32x2 pk;
        pk[0] = cvtpk(s[4*g2+0], s[4*g2+1]);
        pk[1] = cvtpk(s[4*g2+2], s[4*g2+3]);
        *(u32x2*)(Pw + la*76 + half*32 + 8*g2 + 4*hi) = pk;
      }
      __builtin_amdgcn_wave_barrier();   // intra-wave write->read ordering
      // PV for this half: A = V rows d, B = Pt cols q -> O[d][q=la]
      __builtin_amdgcn_s_setprio(1);
      #pragma unroll
      for (int kst2=0; kst2<2; kst2++){
        const int kst = half*2 + kst2;
        bf16x8 pb = *(const bf16x8*)(Pw + la*76 + kst*16 + hi*8);
        #pragma unroll
        for (int dt=0; dt<4; dt++){
          bf16x8 vf = *(const bf16x8*)(Vs + (dt*32 + la)*64 + (((2*kst + hi) ^ s7) * 8));
          oacc[dt] = mfma32(vf, pb, oacc[dt]);
        }
      }
      __builtin_amdgcn_s_setprio(0);
    }
  }
  // total row sum; normalize; write bf16 partial O (row q = la) + (m,l)
  const float lt = lsum + __shfl_xor(lsum, 32);
  const float linv = 1.f / lt;
  unsigned short* Od = opart + ((size_t)(split*NH + h)*NTOK + nbq + la)*DH;
  #pragma unroll
  for (int dt=0;dt<4;dt++)
    #pragma unroll
    for (int g2=0; g2<4; g2++){
      unsigned short pk[4] __attribute__((aligned(8)));
      #pragma unroll
      for (int j=0;j<4;j++) pk[j] = f2bf(oacc[dt][4*g2+j] * linv);
      *(short4v*)(Od + dt*32 + 8*g2 + 4*hi) = *(const short4v*)pk;
    }
  if (hi == 0){
    float* ml = mlbuf + ((size_t)(split*NH + h)*NTOK + nbq)*2;
    ml[la*2]     = mk * INV_KSC;
    ml[la*2 + 1] = lt;
  }
}

// ---------------- merge kv-splits -> ao_t (N,C) bf16 ----------------
template<int NS>
__global__ __launch_bounds__(256) void k_merge(const unsigned short* __restrict__ opart,
                                               const float* __restrict__ mlbuf,
                                               unsigned short* __restrict__ ao_t){
  const int h = blockIdx.y;
  const int n = blockIdx.x*2 + (threadIdx.x >> 7);
  const int d = threadIdx.x & 127;
  float ms[NS], ls[NS], m = -1e30f;
  #pragma unroll
  for (int s=0;s<NS;s++){
    const float* ml = mlbuf + ((size_t)(s*NH + h)*NTOK + n)*2;
    ms[s] = ml[0]; ls[s] = ml[1];
    m = fmaxf(m, ms[s]);
  }
  float wsum = 0.f, o = 0.f;
  #pragma unroll
  for (int s=0;s<NS;s++){
    float wgt = exp2f((ms[s]-m)*KSC) * ls[s];
    wsum += wgt;
    o += wgt * bf2f(opart[((size_t)(s*NH + h)*NTOK + n)*DH + d]);
  }
  ao_t[(size_t)n*CDIM + h*DH + d] = f2bf(o / wsum);
}

extern "C" void kernel_launch(void* const* d_in, const int* in_sizes, int n_in,
                              void* d_out, int out_size, void* d_ws, size_t ws_size,
                              hipStream_t stream){
  const float* x      = (const float*)d_in[0];
  const float* norm_w = (const float*)d_in[1];
  const float* norm_b = (const float*)d_in[2];
  const float* qkv_w  = (const float*)d_in[3];
  const float* qkv_b  = (const float*)d_in[4];
  const float* proj_w = (const float*)d_in[5];
  const float* proj_b = (const float*)d_in[6];
  float* out = (float*)d_out;

  char* ws = (char*)d_ws;
  unsigned short* qw  = (unsigned short*)(ws);             // 1536x512 bf16
  unsigned short* pw  = (unsigned short*)(ws + 1572864);   // 512x512 bf16
  unsigned short* h_t = (unsigned short*)(ws + 2097152);   // 4096x512 bf16
  unsigned short* q_t = (unsigned short*)(ws + 6291456);   // 4x4096x128 bf16
  unsigned short* k_t = (unsigned short*)(ws + 10485760);  // 4x4096x128 bf16
  unsigned short* vb  = (unsigned short*)(ws + 14680064);  // 4x128x4096 bf16
  unsigned short* ao  = (unsigned short*)(ws + 18874368);  // 4096x512 bf16
  float* stats        = (float*)(ws + 23068672);           // 64 floats
  unsigned short* opart = (unsigned short*)(ws + 23072768);// NS x4x4096x128 bf16

  hipLaunchKernelGGL(k_convert, dim3(1024), dim3(256), 0, stream, qkv_w, proj_w, qw, pw);
  hipLaunchKernelGGL(k_gnstats, dim3(32), dim3(256), 0, stream, x, stats);
  hipLaunchKernelGGL(k_gnapply, dim3(64, 8), dim3(256), 0, stream, x, stats, norm_w, norm_b, h_t);
  hipLaunchKernelGGL((k_gemm<0>), dim3(32, 12), dim3(256), 0, stream,
                     qw, h_t, qkv_b, (const float*)nullptr,
                     q_t, k_t, vb, (float*)nullptr, 512);

  // NS=8 needs 23072768 + 32MB opart + 1MB ml = 57,675,776 B of ws
  if (ws_size >= 57675776ULL){
    constexpr int NS = 8;
    float* mlbuf = (float*)(ws + 23072768 + (size_t)NS*NH*NTOK*DH*2);
    hipLaunchKernelGGL((k_attn<NS>), dim3((NTOK/128)*NS, NH), dim3(256), 0, stream,
                       q_t, k_t, vb, opart, mlbuf);
    hipLaunchKernelGGL((k_merge<NS>), dim3(NTOK/2, NH), dim3(256), 0, stream, opart, mlbuf, ao);
  } else {
    constexpr int NS = 4;
    float* mlbuf = (float*)(ws + 23072768 + (size_t)NS*NH*NTOK*DH*2);
    hipLaunchKernelGGL((k_attn<NS>), dim3((NTOK/128)*NS, NH), dim3(256), 0, stream,
                       q_t, k_t, vb, opart, mlbuf);
    hipLaunchKernelGGL((k_merge<NS>), dim3(NTOK/2, NH), dim3(256), 0, stream, opart, mlbuf, ao);
  }

  hipLaunchKernelGGL((k_gemm<1>), dim3(32, 4), dim3(256), 0, stream,
                     pw, ao, proj_b, x,
                     (unsigned short*)nullptr, (unsigned short*)nullptr, (unsigned short*)nullptr, out, 512);
}

// Round 14
// 116.067 us; speedup vs baseline: 1.1898x; 1.1898x over previous
//
#include <hip/hip_runtime.h>
#include <hip/hip_bf16.h>

#define CDIM 512
#define NTOK 4096
#define NH 4
#define DH 128
#define NGRP 32
#define EPS 1e-5f
#define NSPLIT 4
#define KVBLK 64
#define TPS (NTOK/KVBLK/NSPLIT)   // 16 tiles per split

typedef __attribute__((ext_vector_type(8))) short bf16x8;
typedef __attribute__((ext_vector_type(4))) short short4v;
typedef __attribute__((ext_vector_type(4))) float f32x4;
typedef __attribute__((ext_vector_type(16))) float f32x16;
typedef __attribute__((ext_vector_type(4))) unsigned int u32x4;

__device__ inline unsigned short f2bf(float f){
  unsigned int u = __float_as_uint(f);
  u = (u + 0x7fffu + ((u >> 16) & 1u)) >> 16;
  return (unsigned short)u;
}

__device__ inline float bf2f(unsigned short u){
  return __uint_as_float(((unsigned int)u) << 16);
}

__device__ inline f32x4 mfma_bf16(bf16x8 a, bf16x8 b, f32x4 c){
  asm("v_mfma_f32_16x16x32_bf16 %0, %1, %2, %0" : "+v"(c) : "v"(a), "v"(b));
  return c;
}

__device__ inline f32x16 mfma32(bf16x8 a, bf16x8 b, f32x16 c){
  asm("v_mfma_f32_32x32x16_bf16 %0, %1, %2, %0" : "+v"(c) : "v"(a), "v"(b));
  return c;
}

__device__ inline unsigned int cvtpk(float lo, float hi){
  unsigned int r;
  asm("v_cvt_pk_bf16_f32 %0, %1, %2" : "=v"(r) : "v"(lo), "v"(hi));
  return r;
}

#define GLD16(gsrc, ldst) \
  __builtin_amdgcn_global_load_lds((__attribute__((address_space(1))) const void*)(gsrc), \
                                   (__attribute__((address_space(3))) void*)(ldst), 16, 0, 0)

// P = exp(scale*(s-m)) = exp2(s*KSC - m*KSC)
#define KSC (0.088388347648318447f * 1.4426950408889634f)
#define INV_KSC (1.0f / KSC)
#define THR_RAW 60.0f
#define THR_K (THR_RAW * KSC)

// ---------------- fused: weight fp32->bf16 convert + groupnorm stats ----------------
// blocks 0..31: gnstats (one per group); blocks 32..1055: convert (grid-stride).
__global__ __launch_bounds__(256) void k_prep(const float* __restrict__ qkv_w,
                                              const float* __restrict__ proj_w,
                                              unsigned short* __restrict__ qw,
                                              unsigned short* __restrict__ pw,
                                              const float* __restrict__ x,
                                              float* __restrict__ stats){
  const int t = threadIdx.x;
  __shared__ float rs[4], rss[4];
  if (blockIdx.x < 32){
    const int g = blockIdx.x;
    const f32x4* p = (const f32x4*)(x + (size_t)g * (16*NTOK));
    float s = 0.f, ss = 0.f;
    for (int i = t; i < 16*NTOK/4; i += 256){
      f32x4 v = p[i];
      s  += v[0]+v[1]+v[2]+v[3];
      ss += v[0]*v[0]+v[1]*v[1]+v[2]*v[2]+v[3]*v[3];
    }
    for (int off = 32; off > 0; off >>= 1){ s += __shfl_down(s, off); ss += __shfl_down(ss, off); }
    if ((t & 63) == 0){ rs[t>>6] = s; rss[t>>6] = ss; }
    __syncthreads();
    if (t == 0){
      float S  = rs[0]+rs[1]+rs[2]+rs[3];
      float SS = rss[0]+rss[1]+rss[2]+rss[3];
      const float inv = 1.f / (float)(16*NTOK);
      float mu  = S * inv;
      float var = SS * inv - mu*mu;
      stats[g]        = mu;
      stats[NGRP + g] = rsqrtf(var + EPS);
    }
  } else {
    const int stride = 1024 * 256;
    const int i0 = (blockIdx.x - 32) * 256 + t;
    for (int i = i0; i < 3*CDIM*CDIM; i += stride) qw[i] = f2bf(qkv_w[i]);
    for (int i = i0; i < CDIM*CDIM; i += stride)   pw[i] = f2bf(proj_w[i]);
  }
}

// ---------------- GN apply + transpose: x (C,N) fp32 -> h_t (N,C) bf16 ----------------
__global__ __launch_bounds__(256) void k_gnapply(const float* __restrict__ x,
                                                 const float* __restrict__ stats,
                                                 const float* __restrict__ nw,
                                                 const float* __restrict__ nbias,
                                                 unsigned short* __restrict__ h_t){
  __shared__ float tile[64][68];
  const int n0 = blockIdx.x * 64, c0 = blockIdx.y * 64;
  const int t = threadIdx.x;
  {
    const int cl = t >> 2;
    #pragma unroll
    for (int i = 0; i < 4; i++){
      const int f4 = (t & 3) + i*4;
      *(f32x4*)&tile[cl][f4*4] = *(const f32x4*)(x + (size_t)(c0+cl)*NTOK + n0 + f4*4);
    }
  }
  __syncthreads();
  const int nl = t >> 2, cb = (t & 3) * 16;
  unsigned short ov[16] __attribute__((aligned(8)));
  #pragma unroll
  for (int j = 0; j < 16; j++){
    const int c = c0 + cb + j;
    const int grp = c >> 4;
    const float val = (tile[cb+j][nl] - stats[grp]) * stats[NGRP+grp] * nw[c] + nbias[c];
    ov[j] = f2bf(val);
  }
  unsigned short* dst = h_t + (size_t)(n0+nl)*CDIM + c0 + cb;
  #pragma unroll
  for (int j = 0; j < 4; j++) *(short4v*)(dst + j*4) = *(const short4v*)(ov + j*4);
}

// ---------------- GEMM: A (M,K) bf16 row-major, Bt (N,K) bf16 row-major ----------------
template<int MODE>
__global__ __launch_bounds__(256) void k_gemm(const unsigned short* __restrict__ A,
                                              const unsigned short* __restrict__ Bt,
                                              const float* __restrict__ bias,
                                              const float* __restrict__ xres,
                                              unsigned short* __restrict__ q_t,
                                              unsigned short* __restrict__ k_t,
                                              unsigned short* __restrict__ vbuf,
                                              float* __restrict__ out,
                                              int K)
{
  __shared__ unsigned short Asm[128*32];
  __shared__ unsigned short Bsm[128*32];
  const int m0 = blockIdx.y * 128, n0 = blockIdx.x * 128;
  const int t = threadIdx.x;
  const int lane = t & 63, w = t >> 6;
  const int lo = lane & 15, g = lane >> 4;
  const int wr = w >> 1, wc = w & 1;
  f32x4 acc[4][4];
  #pragma unroll
  for (int i=0;i<4;i++)
    #pragma unroll
    for (int j=0;j<4;j++) acc[i][j] = f32x4{0.f,0.f,0.f,0.f};

  const int row = t >> 2, cb8 = (t & 3) * 8;
  for (int k0 = 0; k0 < K; k0 += 32){
    __syncthreads();
    *(bf16x8*)(Asm + row*32 + cb8)      = *(const bf16x8*)(A  + (size_t)(m0+row)*K    + k0 + cb8);
    *(bf16x8*)(Asm + (row+64)*32 + cb8) = *(const bf16x8*)(A  + (size_t)(m0+row+64)*K + k0 + cb8);
    *(bf16x8*)(Bsm + row*32 + cb8)      = *(const bf16x8*)(Bt + (size_t)(n0+row)*K    + k0 + cb8);
    *(bf16x8*)(Bsm + (row+64)*32 + cb8) = *(const bf16x8*)(Bt + (size_t)(n0+row+64)*K + k0 + cb8);
    __syncthreads();
    bf16x8 af[4], bfr[4];
    #pragma unroll
    for (int i=0;i<4;i++) af[i]  = *(const bf16x8*)(Asm + (wr*64 + i*16 + lo)*32 + g*8);
    #pragma unroll
    for (int j=0;j<4;j++) bfr[j] = *(const bf16x8*)(Bsm + (wc*64 + j*16 + lo)*32 + g*8);
    #pragma unroll
    for (int i=0;i<4;i++)
      #pragma unroll
      for (int j=0;j<4;j++)
        acc[i][j] = mfma_bf16(af[i], bfr[j], acc[i][j]);
  }

  if constexpr (MODE == 0){
    const int sQ = m0 >> 9;
    const int hh = (m0 >> 7) & 3;
    #pragma unroll
    for (int i=0;i<4;i++){
      const int ddb = wr*64 + i*16 + g*4;
      const int ob  = m0 + ddb;
      float b[4];
      #pragma unroll
      for (int r=0;r<4;r++) b[r] = bias[ob + r];
      #pragma unroll
      for (int j=0;j<4;j++){
        const int n = n0 + wc*64 + j*16 + lo;
        if (sQ < 2){
          unsigned short pk[4] __attribute__((aligned(8)));
          #pragma unroll
          for (int r=0;r<4;r++) pk[r] = f2bf(acc[i][j][r] + b[r]);
          unsigned short* dst = (sQ == 0 ? q_t : k_t) + ((size_t)hh*NTOK + n)*DH + ddb;
          *(short4v*)dst = *(const short4v*)pk;
        } else {
          #pragma unroll
          for (int r=0;r<4;r++)
            vbuf[((size_t)hh*DH + ddb + r)*NTOK + n] = f2bf(acc[i][j][r] + b[r]);
        }
      }
    }
  } else {
    #pragma unroll
    for (int i=0;i<4;i++){
      const int ob = m0 + wr*64 + i*16 + g*4;
      float b[4];
      #pragma unroll
      for (int r=0;r<4;r++) b[r] = bias[ob + r];
      #pragma unroll
      for (int j=0;j<4;j++){
        const int n = n0 + wc*64 + j*16 + lo;
        #pragma unroll
        for (int r=0;r<4;r++){
          size_t idx = (size_t)(ob + r)*NTOK + n;
          out[idx] = acc[i][j][r] + b[r] + xres[idx];
        }
      }
    }
  }
}

// ---------------- flash attention: round-8 math (in-register P) in round-12 shell ----------------
// 256 threads / 4 waves / 128 q rows; NSPLIT=4; single-buffered K/V (32 KB LDS).
// K tile [64][128] chunk16 swizzle ^(row&15); V tile [128][64] ^(row&7).
// Swapped QK^T (single chain); lane la = q col; in-lane softmax; P assembled in-register
// via cvtpk + shfl_xor(32) + select (round-8-verified); PV: A=P, B=V^T -> O[q regs][d=la].
__global__ __launch_bounds__(256, 2) void k_attn(const unsigned short* __restrict__ q_t,
                                                 const unsigned short* __restrict__ k_t,
                                                 const unsigned short* __restrict__ vbuf,
                                                 unsigned short* __restrict__ opart,
                                                 float* __restrict__ mlbuf){
  const int h = blockIdx.y;
  const int qt = blockIdx.x >> 2, split = blockIdx.x & 3;
  const int t = threadIdx.x, w = t >> 6, lane = t & 63;
  const int la = lane & 31, hi = lane >> 5;
  const int s15 = la & 15, s7 = la & 7;
  const int nbq = qt * 128 + w * 32;

  __shared__ __align__(16) unsigned short Ksm[64*128];
  __shared__ __align__(16) unsigned short Vsm[128*64];

  const unsigned short* kg = k_t  + (size_t)h*NTOK*DH;
  const unsigned short* vg = vbuf + (size_t)h*DH*NTOK;

  auto stage = [&](int mt){
    const unsigned short* kgm = kg + (size_t)mt*KVBLK*DH;
    const unsigned short* vgm = vg + mt*KVBLK;
    #pragma unroll
    for (int rnd = 0; rnd < 4; rnd++){       // K: 1024 chunks / 256 threads
      const int c = rnd*256 + t;
      const int row = c >> 4, col = c & 15;
      GLD16(kgm + (size_t)row*DH + ((col ^ (row & 15))*8), &Ksm[c*8]);
    }
    #pragma unroll
    for (int rnd = 0; rnd < 4; rnd++){       // V: 1024 chunks / 256 threads
      const int c = rnd*256 + t;
      const int row = c >> 3, col = c & 7;
      GLD16(vgm + (size_t)row*NTOK + ((col ^ (row & 7))*8), &Vsm[c*8]);
    }
  };

  // Q as B-operand: col = q = la, k-slice d = ks*16 + hi*8 + j
  bf16x8 qa[8];
  {
    const unsigned short* qr = q_t + ((size_t)h*NTOK + nbq + la)*DH + hi*8;
    #pragma unroll
    for (int ks=0;ks<8;ks++) qa[ks] = *(const bf16x8*)(qr + ks*16);
  }

  float mk = -1e30f;      // running max * KSC for q = la
  float lsum = 0.f;       // own-hi partial row sum for q = la
  f32x16 oacc[4];         // O[q = crow(r,hi)][d = dt*32 + la]
  #pragma unroll
  for (int dt=0;dt<4;dt++)
    #pragma unroll
    for (int r=0;r<16;r++) oacc[dt][r] = 0.f;

  const int mt0 = split * TPS;
  for (int it = 0; it < TPS; it++){
    __syncthreads();                 // all waves done reading previous tile
    stage(mt0 + it);
    __syncthreads();                 // stage drained (compiler emits vmcnt(0) before barrier)

    const unsigned short* Ks = Ksm;
    const unsigned short* Vs = Vsm;

    #pragma unroll
    for (int half = 0; half < 2; half++){
      // swapped QK^T: A = K rows (kv = half*32 + la), B = Q cols (q = la)
      f32x16 s;
      #pragma unroll
      for (int r=0;r<16;r++) s[r] = 0.f;
      __builtin_amdgcn_s_setprio(1);
      #pragma unroll
      for (int ks=0; ks<8; ks++){
        bf16x8 kf = *(const bf16x8*)(Ks + (half*32 + la)*128 + (((2*ks + hi) ^ s15) * 8));
        s = mfma32(kf, qa[ks], s);
      }
      __builtin_amdgcn_s_setprio(0);
      // in-lane max + partner-hi combine; defer-max
      float hmax = s[0];
      #pragma unroll
      for (int r=1;r<16;r++) hmax = fmaxf(hmax, s[r]);
      hmax = fmaxf(hmax, __shfl_xor(hmax, 32));
      const float hk = hmax * KSC;
      if (!__all(hk <= mk + THR_K)){
        const float mnk = fmaxf(mk, hk);
        const float al  = exp2f(mk - mnk);
        mk = mnk;
        lsum *= al;
        #pragma unroll
        for (int r=0;r<16;r++){
          const float a = __shfl(al, (r&3) + 8*(r>>2) + 4*hi);   // alpha for q = crow(r,hi)
          #pragma unroll
          for (int dt=0;dt<4;dt++) oacc[dt][r] *= a;
        }
      }
      // exp in place + own-lane sum
      #pragma unroll
      for (int r=0;r<16;r++){
        s[r] = exp2f(fmaf(s[r], KSC, -mk));
        lsum += s[r];
      }
      // pack to PV A-fragments (round-8-verified): pa[b] covers kv = half*32 + b*16 + hi*8 + j
      bf16x8 paf[2];
      #pragma unroll
      for (int b=0;b<2;b++){
        unsigned int A = cvtpk(s[8*b+0], s[8*b+1]);
        unsigned int B = cvtpk(s[8*b+2], s[8*b+3]);
        unsigned int C = cvtpk(s[8*b+4], s[8*b+5]);
        unsigned int D = cvtpk(s[8*b+6], s[8*b+7]);
        unsigned int E = hi ? A : C;
        unsigned int F = hi ? B : D;
        E = (unsigned int)__shfl_xor((int)E, 32);
        F = (unsigned int)__shfl_xor((int)F, 32);
        u32x4 m;
        m[0] = hi ? E : A;
        m[1] = hi ? F : B;
        m[2] = hi ? C : E;
        m[3] = hi ? D : F;
        paf[b] = __builtin_bit_cast(bf16x8, m);
      }
      // PV for this half: A = P rows q, B = V^T cols d -> O[q][d=la]
      __builtin_amdgcn_s_setprio(1);
      #pragma unroll
      for (int dt=0; dt<4; dt++){
        const int vbase = (dt*32 + la)*64;
        bf16x8 vf0 = *(const bf16x8*)(Vs + vbase + (((2*(half*2+0) + hi) ^ s7) * 8));
        bf16x8 vf1 = *(const bf16x8*)(Vs + vbase + (((2*(half*2+1) + hi) ^ s7) * 8));
        oacc[dt] = mfma32(paf[0], vf0, oacc[dt]);
        oacc[dt] = mfma32(paf[1], vf1, oacc[dt]);
      }
      __builtin_amdgcn_s_setprio(0);
    }
  }
  // total row sum; normalize; write bf16 partial O (rows q in regs, col d = la) + (m,l)
  const float lt = lsum + __shfl_xor(lsum, 32);
  unsigned short* Od = opart + ((size_t)(split*NH + h)*NTOK + nbq)*DH;
  #pragma unroll
  for (int r=0;r<16;r++){
    const int q = (r&3) + 8*(r>>2) + 4*hi;
    const float linv = 1.f / __shfl(lt, q);
    #pragma unroll
    for (int dt=0;dt<4;dt++)
      Od[(size_t)q*DH + dt*32 + la] = f2bf(oacc[dt][r] * linv);
  }
  if (hi == 0){
    float* ml = mlbuf + ((size_t)(split*NH + h)*NTOK + nbq)*2;
    ml[la*2]     = mk * INV_KSC;
    ml[la*2 + 1] = lt;
  }
}

// ---------------- merge kv-splits -> ao_t (N,C) bf16 ----------------
__global__ __launch_bounds__(256) void k_merge(const unsigned short* __restrict__ opart,
                                               const float* __restrict__ mlbuf,
                                               unsigned short* __restrict__ ao_t){
  const int h = blockIdx.y;
  const int n = blockIdx.x*2 + (threadIdx.x >> 7);
  const int d = threadIdx.x & 127;
  float ms[NSPLIT], ls[NSPLIT], m = -1e30f;
  #pragma unroll
  for (int s=0;s<NSPLIT;s++){
    const float* ml = mlbuf + ((size_t)(s*NH + h)*NTOK + n)*2;
    ms[s] = ml[0]; ls[s] = ml[1];
    m = fmaxf(m, ms[s]);
  }
  float wsum = 0.f, o = 0.f;
  #pragma unroll
  for (int s=0;s<NSPLIT;s++){
    float wgt = exp2f((ms[s]-m)*KSC) * ls[s];
    wsum += wgt;
    o += wgt * bf2f(opart[((size_t)(s*NH + h)*NTOK + n)*DH + d]);
  }
  ao_t[(size_t)n*CDIM + h*DH + d] = f2bf(o / wsum);
}

extern "C" void kernel_launch(void* const* d_in, const int* in_sizes, int n_in,
                              void* d_out, int out_size, void* d_ws, size_t ws_size,
                              hipStream_t stream){
  const float* x      = (const float*)d_in[0];
  const float* norm_w = (const float*)d_in[1];
  const float* norm_b = (const float*)d_in[2];
  const float* qkv_w  = (const float*)d_in[3];
  const float* qkv_b  = (const float*)d_in[4];
  const float* proj_w = (const float*)d_in[5];
  const float* proj_b = (const float*)d_in[6];
  float* out = (float*)d_out;

  char* ws = (char*)d_ws;
  unsigned short* qw  = (unsigned short*)(ws);             // 1536x512 bf16
  unsigned short* pw  = (unsigned short*)(ws + 1572864);   // 512x512 bf16
  unsigned short* h_t = (unsigned short*)(ws + 2097152);   // 4096x512 bf16
  unsigned short* q_t = (unsigned short*)(ws + 6291456);   // 4x4096x128 bf16
  unsigned short* k_t = (unsigned short*)(ws + 10485760);  // 4x4096x128 bf16
  unsigned short* vb  = (unsigned short*)(ws + 14680064);  // 4x128x4096 bf16
  unsigned short* ao  = (unsigned short*)(ws + 18874368);  // 4096x512 bf16
  float* stats        = (float*)(ws + 23068672);           // 64 floats
  unsigned short* opart = (unsigned short*)(ws + 23072768);// 4x4x4096x128 bf16 = 16 MB
  float* mlbuf        = (float*)(ws + 39849984);           // 4x4x4096x2 f32 = 512 KB
  // end ≈ 40.4 MB of d_ws (proven footprint)

  hipLaunchKernelGGL(k_prep, dim3(1056), dim3(256), 0, stream, qkv_w, proj_w, qw, pw, x, stats);
  hipLaunchKernelGGL(k_gnapply, dim3(64, 8), dim3(256), 0, stream, x, stats, norm_w, norm_b, h_t);
  hipLaunchKernelGGL((k_gemm<0>), dim3(32, 12), dim3(256), 0, stream,
                     qw, h_t, qkv_b, (const float*)nullptr,
                     q_t, k_t, vb, (float*)nullptr, 512);
  hipLaunchKernelGGL(k_attn, dim3(32*NSPLIT, NH), dim3(256), 0, stream, q_t, k_t, vb, opart, mlbuf);
  hipLaunchKernelGGL(k_merge, dim3(NTOK/2, NH), dim3(256), 0, stream, opart, mlbuf, ao);
  hipLaunchKernelGGL((k_gemm<1>), dim3(32, 4), dim3(256), 0, stream,
                     pw, ao, proj_b, x,
                     (unsigned short*)nullptr, (unsigned short*)nullptr, (unsigned short*)nullptr, out, 512);
}